// Round 2
// baseline (122.700 us; speedup 1.0000x reference)
//
#include <hip/hip_runtime.h>
#include <hip/hip_bf16.h>
#include <stdint.h>

#define NN 50000
#define DD 128
#define PP 6
#define LL 6
#define CHUNK 32       // dims per gather pass: 50000*32*2B = 3.2 MB -> fits 4MB per-XCD L2
#define PAD 132        // padded LDS row (128 + 4) -> conflict-free strided reads

typedef float f4 __attribute__((ext_vector_type(4)));

__device__ __forceinline__ uint16_t f2bf(float f) {
  uint32_t u = __float_as_uint(f);
  u = (u + 0x7fffu + ((u >> 16) & 1u)) >> 16;   // round-to-nearest-even
  return (uint16_t)u;
}

// ---- kernel 0: feats f32 -> bf16 (halves gather traffic) ----
__global__ __launch_bounds__(256) void k_cvt(const float* __restrict__ in,
                                             uint16_t* __restrict__ out, int n4) {
  int i = blockIdx.x * 256 + threadIdx.x;
  if (i >= n4) return;
  f4 v = ((const f4*)in)[i];
  ushort4 o;
  o.x = f2bf(v.x); o.y = f2bf(v.y); o.z = f2bf(v.z); o.w = f2bf(v.w);
  ((ushort4*)out)[i] = o;
}

// ---- kernel 1 (x4 chunk launches): acc[n, c0:c0+32] = (1/6) sum_{p,l} w[l,c]*fb[paths[p,n,l], c]
// 16 lanes per node, 1 dword (2 bf16) per lane: 64 B per gather, feats chunk L2-resident.
__global__ __launch_bounds__(256) void k_gather(
    const uint16_t* __restrict__ fb,     // (NN, DD) bf16
    const int* __restrict__ paths,       // (PP, NN, LL) int32
    const float* __restrict__ w,         // (LL, DD) f32  (= path_weight1[0])
    float* __restrict__ acc,             // (NN, DD) f32
    int c0) {                            // chunk dim offset
  const int lane = threadIdx.x & 15;
  const int grp  = threadIdx.x >> 4;     // 0..15
  const int n    = blockIdx.x * 16 + grp;
  const int d    = c0 + lane * 2;

  const float s = 1.f / 6.f;
  float wx[LL], wy[LL];
  #pragma unroll
  for (int l = 0; l < LL; ++l) {
    wx[l] = w[l * DD + d]     * s;
    wy[l] = w[l * DD + d + 1] * s;
  }

  if (n >= NN) return;

  const int* pn = paths + (size_t)n * LL;     // stride PP dimension manually
  float ax = 0.f, ay = 0.f;
  #pragma unroll
  for (int p = 0; p < PP; ++p) {
    #pragma unroll
    for (int l = 0; l < LL; ++l) {
      const int idx = pn[(size_t)p * NN * LL + l];
      const uint32_t v = *(const uint32_t*)(fb + (size_t)idx * DD + d);  // 2 bf16
      const float f0 = __uint_as_float(v << 16);
      const float f1 = __uint_as_float(v & 0xffff0000u);
      ax = fmaf(wx[l], f0, ax);
      ay = fmaf(wy[l], f1, ay);
    }
  }
  float2 o; o.x = ax; o.y = ay;
  *(float2*)(acc + (size_t)n * DD + d) = o;
}

// ---- kernel 2: out = relu(acc @ W^T), W (128,128) row-major (o,d) ----
__global__ __launch_bounds__(256) void k_fc(
    const float* __restrict__ acc,
    const float* __restrict__ fcw,
    float* __restrict__ out) {
  __shared__ float sA[64 * PAD];
  __shared__ float sW[64 * PAD];
  const int t = threadIdx.x;
  const int nb = blockIdx.x * 64;

  #pragma unroll
  for (int it = 0; it < 8; ++it) {
    const int i = it * 1024 + t * 4;
    const int r = i >> 7, c = i & 127;
    f4 v = {0.f, 0.f, 0.f, 0.f};
    if (nb + r < NN) v = *(const f4*)(acc + (size_t)(nb + r) * DD + c);
    *(f4*)(sA + r * PAD + c) = v;
  }

  const int tx = t & 15, ty = t >> 4;

  #pragma unroll
  for (int ob = 0; ob < 2; ++ob) {
    __syncthreads();                      // protect sW reuse across ob
    #pragma unroll
    for (int it = 0; it < 8; ++it) {
      const int i = it * 1024 + t * 4;
      const int r = i >> 7, c = i & 127;
      *(f4*)(sW + r * PAD + c) = *(const f4*)(fcw + (size_t)(ob * 64 + r) * DD + c);
    }
    __syncthreads();

    float ao[4][4];
    #pragma unroll
    for (int i = 0; i < 4; ++i)
      #pragma unroll
      for (int j = 0; j < 4; ++j) ao[i][j] = 0.f;

    for (int dd0 = 0; dd0 < DD; dd0 += 4) {
      f4 an[4], wo[4];
      #pragma unroll
      for (int i = 0; i < 4; ++i) an[i] = *(const f4*)(sA + (ty * 4 + i) * PAD + dd0);
      #pragma unroll
      for (int j = 0; j < 4; ++j) wo[j] = *(const f4*)(sW + (tx + 16 * j) * PAD + dd0);
      #pragma unroll
      for (int i = 0; i < 4; ++i)
        #pragma unroll
        for (int j = 0; j < 4; ++j) {
          ao[i][j] = fmaf(an[i].x, wo[j].x, ao[i][j]);
          ao[i][j] = fmaf(an[i].y, wo[j].y, ao[i][j]);
          ao[i][j] = fmaf(an[i].z, wo[j].z, ao[i][j]);
          ao[i][j] = fmaf(an[i].w, wo[j].w, ao[i][j]);
        }
    }

    #pragma unroll
    for (int i = 0; i < 4; ++i) {
      const int n = nb + ty * 4 + i;
      if (n >= NN) continue;
      #pragma unroll
      for (int j = 0; j < 4; ++j) {
        const int o = ob * 64 + tx + 16 * j;
        out[(size_t)n * DD + o] = fmaxf(ao[i][j], 0.f);
      }
    }
  }
}

extern "C" void kernel_launch(void* const* d_in, const int* in_sizes, int n_in,
                              void* d_out, int out_size, void* d_ws, size_t ws_size,
                              hipStream_t stream) {
  const float* feats = (const float*)d_in[0];
  const int*   paths = (const int*)d_in[1];       // int32 (jax x64 disabled)
  const float* pw1   = (const float*)d_in[4];     // (1,6,128) -> flat (6,128)
  const float* fcw   = (const float*)d_in[6];     // (128,128)
  float* out = (float*)d_out;

  uint16_t* fb  = (uint16_t*)d_ws;                                  // 12.8 MB
  float*    acc = (float*)((char*)d_ws + (size_t)NN * DD * 2);      // 25.6 MB

  const int n4 = NN * DD / 4;
  k_cvt<<<(n4 + 255) / 256, 256, 0, stream>>>(feats, fb, n4);

  const int gblocks = (NN + 15) / 16;   // 16 nodes per 256-thread block
  for (int c = 0; c < 4; ++c)
    k_gather<<<gblocks, 256, 0, stream>>>(fb, paths, pw1, acc, c * CHUNK);

  k_fc<<<(NN + 63) / 64, 256, 0, stream>>>(acc, fcw, out);
}

// Round 4
// 84.656 us; speedup vs baseline: 1.4494x; 1.4494x over previous
//
#include <hip/hip_runtime.h>
#include <stdint.h>

#define NN 50000
#define DD 128
#define PP 6
#define LL 6
#define NPG 4          // nodes per 32-lane group in gather kernel (round-1 known-good)
#define WPAD 136       // bf16 LDS row stride (128+8): 272B rows, 16B-aligned, 2-way bank aliasing (free)

typedef float f4 __attribute__((ext_vector_type(4)));
typedef short bf16x8 __attribute__((ext_vector_type(8)));

__device__ __forceinline__ uint16_t f2bf(float f) {
  uint32_t u = __float_as_uint(f);
  u = (u + 0x7fffu + ((u >> 16) & 1u)) >> 16;   // RNE
  return (uint16_t)u;
}
__device__ __forceinline__ float bf_lo(uint32_t u) { return __uint_as_float(u << 16); }
__device__ __forceinline__ float bf_hi(uint32_t u) { return __uint_as_float(u & 0xffff0000u); }

// ---- kernel 0: feats f32 -> bf16 (halves gather traffic) ----
__global__ __launch_bounds__(256) void k_cvt(const float* __restrict__ in,
                                             uint16_t* __restrict__ out, int n4) {
  int i = blockIdx.x * 256 + threadIdx.x;
  if (i >= n4) return;
  f4 v = ((const f4*)in)[i];
  ushort4 o;
  o.x = f2bf(v.x); o.y = f2bf(v.y); o.z = f2bf(v.z); o.w = f2bf(v.w);
  ((ushort4*)out)[i] = o;
}

// ---- kernel 1: gather-weighted accumulate (ROUND-1 VERBATIM, known good) ----
// acc[n,:] = (1/6) sum_{p,l} w[l,:]*feats_bf16[paths[p,n,l],:]
__global__ __launch_bounds__(256) void k_gather(
    const uint16_t* __restrict__ fb,     // (NN, DD) bf16
    const int* __restrict__ paths,       // (PP, NN, LL) int32
    const float* __restrict__ w,         // (LL, DD) f32  (= path_weight1[0])
    float* __restrict__ acc) {           // (NN, DD) f32
  const int lane = threadIdx.x & 31;
  const int grp  = threadIdx.x >> 5;     // 0..7
  const int d0   = lane * 4;
  const int nbase = blockIdx.x * (8 * NPG) + grp * NPG;

  f4 wl[LL];
  #pragma unroll
  for (int l = 0; l < LL; ++l)
    wl[l] = *(const f4*)(w + l * DD + d0);

  #pragma unroll
  for (int ni = 0; ni < NPG; ++ni) {
    const int n = nbase + ni;
    if (n >= NN) return;                 // uniform within the 32-lane group
    f4 a = {0.f, 0.f, 0.f, 0.f};
    #pragma unroll
    for (int p = 0; p < PP; ++p) {
      #pragma unroll
      for (int l = 0; l < LL; ++l) {
        const int idx = paths[(p * NN + n) * LL + l];
        const uint2 v = *(const uint2*)(fb + idx * DD + d0);   // 4 bf16
        a.x = fmaf(wl[l].x, bf_lo(v.x), a.x);
        a.y = fmaf(wl[l].y, bf_hi(v.x), a.y);
        a.z = fmaf(wl[l].z, bf_lo(v.y), a.z);
        a.w = fmaf(wl[l].w, bf_hi(v.y), a.w);
      }
    }
    const float s = 1.f / 6.f;
    a.x *= s; a.y *= s; a.z *= s; a.w *= s;
    *(f4*)(acc + (size_t)n * DD + d0) = a;
  }
}

// ---- kernel 2: out = relu(acc @ W^T) via mfma_f32_16x16x32_bf16 ----
// Block = 64 nodes, 4 waves; wave w owns rows w*16..w*16+15, all 128 outputs.
__global__ __launch_bounds__(256) void k_fc(
    const float* __restrict__ acc,       // (NN, DD) f32
    const float* __restrict__ fcw,       // (DD, DD) f32, row-major (o, d)
    float* __restrict__ out) {           // (NN, DD) f32
  __shared__ uint16_t sA[64 * WPAD];
  __shared__ uint16_t sW[128 * WPAD];
  const int t = threadIdx.x;
  const int nb = blockIdx.x * 64;

  // stage acc tile 64x128 f32 -> bf16
  #pragma unroll
  for (int it = 0; it < 8; ++it) {
    const int chunk = it * 256 + t;       // 2048 chunks of 4 f32
    const int row = chunk >> 5, c4 = chunk & 31;
    f4 v = {0.f, 0.f, 0.f, 0.f};
    if (nb + row < NN) v = *(const f4*)(acc + (size_t)(nb + row) * DD + c4 * 4);
    ushort4 o;
    o.x = f2bf(v.x); o.y = f2bf(v.y); o.z = f2bf(v.z); o.w = f2bf(v.w);
    *(ushort4*)(sA + row * WPAD + c4 * 4) = o;
  }
  // stage W 128x128 f32 -> bf16
  #pragma unroll
  for (int it = 0; it < 16; ++it) {
    const int chunk = it * 256 + t;       // 4096 chunks of 4 f32
    const int row = chunk >> 5, c4 = chunk & 31;
    f4 v = *(const f4*)(fcw + row * DD + c4 * 4);
    ushort4 o;
    o.x = f2bf(v.x); o.y = f2bf(v.y); o.z = f2bf(v.z); o.w = f2bf(v.w);
    *(ushort4*)(sW + row * WPAD + c4 * 4) = o;
  }
  __syncthreads();

  const int w  = t >> 6;                  // wave 0..3
  const int l  = t & 63;
  const int lr = l & 15;                  // A-row / B-col / D-col
  const int hk = (l >> 4) * 8;            // k sub-offset

  bf16x8 afrag[4];
  #pragma unroll
  for (int k0 = 0; k0 < 4; ++k0)
    afrag[k0] = *(bf16x8*)(sA + (w * 16 + lr) * WPAD + k0 * 32 + hk);

  #pragma unroll
  for (int o = 0; o < 8; ++o) {
    f4 dacc = {0.f, 0.f, 0.f, 0.f};
    #pragma unroll
    for (int k0 = 0; k0 < 4; ++k0) {
      bf16x8 bfrag = *(bf16x8*)(sW + (o * 16 + lr) * WPAD + k0 * 32 + hk);
      dacc = __builtin_amdgcn_mfma_f32_16x16x32_bf16(afrag[k0], bfrag, dacc, 0, 0, 0);
    }
    const int col = o * 16 + lr;
    #pragma unroll
    for (int r = 0; r < 4; ++r) {
      const int n = nb + w * 16 + (l >> 4) * 4 + r;
      if (n < NN) out[(size_t)n * DD + col] = fmaxf(dacc[r], 0.f);
    }
  }
}

extern "C" void kernel_launch(void* const* d_in, const int* in_sizes, int n_in,
                              void* d_out, int out_size, void* d_ws, size_t ws_size,
                              hipStream_t stream) {
  const float* feats = (const float*)d_in[0];
  const int*   paths = (const int*)d_in[1];       // int32 (jax x64 disabled)
  const float* pw1   = (const float*)d_in[4];     // (1,6,128)
  const float* fcw   = (const float*)d_in[6];     // (128,128)
  float* out = (float*)d_out;

  uint16_t* fb  = (uint16_t*)d_ws;                                  // 12.8 MB
  float*    acc = (float*)((char*)d_ws + (size_t)NN * DD * 2);      // 25.6 MB

  const int n4 = NN * DD / 4;
  k_cvt<<<(n4 + 255) / 256, 256, 0, stream>>>(feats, fb, n4);
  k_gather<<<(NN + 8 * NPG - 1) / (8 * NPG), 256, 0, stream>>>(fb, paths, pw1, acc);
  k_fc<<<(NN + 63) / 64, 256, 0, stream>>>(acc, fcw, out);
}

// Round 6
// 82.400 us; speedup vs baseline: 1.4891x; 1.0274x over previous
//
#include <hip/hip_runtime.h>
#include <stdint.h>

#define NN 50000
#define DD 128
#define PP 6
#define LL 6
#define GN 64          // nodes per gather block
#define WPAD 136       // bf16 LDS row stride (128+8): 272B rows, 16B-aligned, 2-way bank aliasing (free)

typedef float f4 __attribute__((ext_vector_type(4)));
typedef short bf16x8 __attribute__((ext_vector_type(8)));

__device__ __forceinline__ uint16_t f2bf(float f) {
  uint32_t u = __float_as_uint(f);
  u = (u + 0x7fffu + ((u >> 16) & 1u)) >> 16;   // RNE
  return (uint16_t)u;
}
__device__ __forceinline__ float bf_lo(uint32_t u) { return __uint_as_float(u << 16); }
__device__ __forceinline__ float bf_hi(uint32_t u) { return __uint_as_float(u & 0xffff0000u); }

// ---- kernel 0: feats f32 -> bf16 (halves gather traffic) ----
__global__ __launch_bounds__(256) void k_cvt(const float* __restrict__ in,
                                             uint16_t* __restrict__ out, int n4) {
  int i = blockIdx.x * 256 + threadIdx.x;
  if (i >= n4) return;
  f4 v = ((const f4*)in)[i];
  ushort4 o;
  o.x = f2bf(v.x); o.y = f2bf(v.y); o.z = f2bf(v.z); o.w = f2bf(v.w);
  ((ushort4*)out)[i] = o;
}

// ---- kernel 1: accb[n,:] = bf16( sum_{p,l} (w[l,:]/6) * fb[paths[p,n,l],:] )
// Indices LDS-staged (coalesced). All 36 gathers issued before FMAs -> max MLP.
__global__ __launch_bounds__(256) void k_gather(
    const uint16_t* __restrict__ fb,     // (NN, DD) bf16
    const int* __restrict__ paths,       // (PP, NN, LL) int32
    const float* __restrict__ w,         // (LL, DD) f32
    uint16_t* __restrict__ accb) {       // (NN, DD) bf16
  __shared__ int sidx[PP * GN * LL];     // [p][n_local][l], 2304 dwords
  const int t = threadIdx.x;
  const int nb = blockIdx.x * GN;

  #pragma unroll
  for (int s = 0; s < 9; ++s) {          // 2304 / 256
    const int i = s * 256 + t;
    const int p = i / (GN * LL);
    const int rem = i - p * (GN * LL);
    const long g = (long)nb * LL + rem;  // dword offset within plane p
    int val = 0;
    if (g < (long)NN * LL) val = paths[(size_t)p * NN * LL + g];
    sidx[i] = val;
  }

  const int lane = t & 31;
  const int grp  = t >> 5;               // 0..7
  const int d0   = lane * 4;

  const float sc = 1.f / 6.f;
  f4 wl[LL];
  #pragma unroll
  for (int l = 0; l < LL; ++l) {
    f4 v = *(const f4*)(w + l * DD + d0);
    wl[l].x = v.x * sc; wl[l].y = v.y * sc; wl[l].z = v.z * sc; wl[l].w = v.w * sc;
  }

  __syncthreads();

  #pragma unroll 1                        // one 36-gather batch in flight per iter
  for (int s = 0; s < 8; ++s) {
    const int ni = grp * 8 + s;
    const int n = nb + ni;
    uint2 v[PP * LL];
    #pragma unroll
    for (int p = 0; p < PP; ++p)
      #pragma unroll
      for (int l = 0; l < LL; ++l) {
        const int idx = sidx[(p * GN + ni) * LL + l];
        v[p * LL + l] = *(const uint2*)(fb + (size_t)idx * DD + d0);  // 4 bf16
      }
    f4 a = {0.f, 0.f, 0.f, 0.f};
    #pragma unroll
    for (int p = 0; p < PP; ++p)
      #pragma unroll
      for (int l = 0; l < LL; ++l) {
        const uint2 u = v[p * LL + l];
        a.x = fmaf(wl[l].x, bf_lo(u.x), a.x);
        a.y = fmaf(wl[l].y, bf_hi(u.x), a.y);
        a.z = fmaf(wl[l].z, bf_lo(u.y), a.z);
        a.w = fmaf(wl[l].w, bf_hi(u.y), a.w);
      }
    if (n < NN) {
      ushort4 o;
      o.x = f2bf(a.x); o.y = f2bf(a.y); o.z = f2bf(a.z); o.w = f2bf(a.w);
      *(ushort4*)(accb + (size_t)n * DD + d0) = o;
    }
  }
}

// ---- kernel 2: out = relu(accb @ W^T) via mfma_f32_16x16x32_bf16 ----
// Block = 64 nodes, 4 waves; wave w owns rows w*16..w*16+15, all 128 outputs.
__global__ __launch_bounds__(256) void k_fc(
    const uint16_t* __restrict__ accb,   // (NN, DD) bf16
    const float* __restrict__ fcw,       // (DD, DD) f32, row-major (o, d)
    float* __restrict__ out) {           // (NN, DD) f32
  __shared__ uint16_t sA[64 * WPAD];
  __shared__ uint16_t sW[128 * WPAD];
  const int t = threadIdx.x;
  const int nb = blockIdx.x * 64;

  // stage acc tile 64x128 bf16: 1024 uint4 chunks (16B = 8 bf16 each), 16 chunks/row
  #pragma unroll
  for (int it = 0; it < 4; ++it) {
    const int chunk = it * 256 + t;       // 1024 chunks
    const int row = chunk >> 4, c8 = chunk & 15;
    uint4 v = {0u, 0u, 0u, 0u};
    if (nb + row < NN) v = *(const uint4*)(accb + (size_t)(nb + row) * DD + c8 * 8);
    *(uint4*)(sA + row * WPAD + c8 * 8) = v;
  }
  // stage W 128x128 f32 -> bf16 (validated in round 4)
  #pragma unroll
  for (int it = 0; it < 16; ++it) {
    const int chunk = it * 256 + t;       // 4096 chunks of 4 f32
    const int row = chunk >> 5, c4 = chunk & 31;
    f4 v = *(const f4*)(fcw + row * DD + c4 * 4);
    ushort4 o;
    o.x = f2bf(v.x); o.y = f2bf(v.y); o.z = f2bf(v.z); o.w = f2bf(v.w);
    *(ushort4*)(sW + row * WPAD + c4 * 4) = o;
  }
  __syncthreads();

  const int w  = t >> 6;                  // wave 0..3
  const int l  = t & 63;
  const int lr = l & 15;                  // A-row / B-col / D-col
  const int hk = (l >> 4) * 8;            // k sub-offset

  bf16x8 afrag[4];
  #pragma unroll
  for (int k0 = 0; k0 < 4; ++k0)
    afrag[k0] = *(bf16x8*)(sA + (w * 16 + lr) * WPAD + k0 * 32 + hk);

  #pragma unroll
  for (int o = 0; o < 8; ++o) {
    f4 dacc = {0.f, 0.f, 0.f, 0.f};
    #pragma unroll
    for (int k0 = 0; k0 < 4; ++k0) {
      bf16x8 bfrag = *(bf16x8*)(sW + (o * 16 + lr) * WPAD + k0 * 32 + hk);
      dacc = __builtin_amdgcn_mfma_f32_16x16x32_bf16(afrag[k0], bfrag, dacc, 0, 0, 0);
    }
    const int col = o * 16 + lr;
    #pragma unroll
    for (int r = 0; r < 4; ++r) {
      const int n = nb + w * 16 + (l >> 4) * 4 + r;
      if (n < NN) out[(size_t)n * DD + col] = fmaxf(dacc[r], 0.f);
    }
  }
}

extern "C" void kernel_launch(void* const* d_in, const int* in_sizes, int n_in,
                              void* d_out, int out_size, void* d_ws, size_t ws_size,
                              hipStream_t stream) {
  const float* feats = (const float*)d_in[0];
  const int*   paths = (const int*)d_in[1];       // int32 (jax x64 disabled)
  const float* pw1   = (const float*)d_in[4];     // (1,6,128)
  const float* fcw   = (const float*)d_in[6];     // (128,128)
  float* out = (float*)d_out;

  uint16_t* fb   = (uint16_t*)d_ws;                                 // 12.8 MB
  uint16_t* accb = (uint16_t*)((char*)d_ws + (size_t)NN * DD * 2);  // 12.8 MB

  const int n4 = NN * DD / 4;
  k_cvt<<<(n4 + 255) / 256, 256, 0, stream>>>(feats, fb, n4);
  k_gather<<<(NN + GN - 1) / GN, 256, 0, stream>>>(fb, paths, pw1, accb);
  k_fc<<<(NN + 63) / 64, 256, 0, stream>>>(accb, fcw, out);
}

// Round 7
// 76.202 us; speedup vs baseline: 1.6102x; 1.0813x over previous
//
#include <hip/hip_runtime.h>
#include <stdint.h>

#define NN 50000
#define DD 128
#define PP 6
#define LL 6
#define GN 64          // nodes per block
#define WPAD 136       // bf16 LDS row stride (128+8): 272B rows (17x16B) keep b128 reads 16B-aligned

typedef float f4 __attribute__((ext_vector_type(4)));
typedef short bf16x8 __attribute__((ext_vector_type(8)));

__device__ __forceinline__ uint16_t f2bf(float f) {
  uint32_t u = __float_as_uint(f);
  u = (u + 0x7fffu + ((u >> 16) & 1u)) >> 16;   // RNE
  return (uint16_t)u;
}
__device__ __forceinline__ float bf_lo(uint32_t u) { return __uint_as_float(u << 16); }
__device__ __forceinline__ float bf_hi(uint32_t u) { return __uint_as_float(u & 0xffff0000u); }

// ---- kernel 0: feats f32 -> bf16 (fb) and fc_weight f32 -> bf16 (wb) ----
__global__ __launch_bounds__(256) void k_cvt(const float* __restrict__ feats,
                                             const float* __restrict__ fcw,
                                             uint16_t* __restrict__ fb,
                                             uint16_t* __restrict__ wb,
                                             int n4, int w4) {
  int i = blockIdx.x * 256 + threadIdx.x;
  const float* src; uint16_t* dst; int j;
  if (i < n4)            { src = feats; dst = fb; j = i; }
  else if (i < n4 + w4)  { src = fcw;   dst = wb; j = i - n4; }
  else return;
  f4 v = ((const f4*)src)[j];
  ushort4 o;
  o.x = f2bf(v.x); o.y = f2bf(v.y); o.z = f2bf(v.z); o.w = f2bf(v.w);
  ((ushort4*)dst)[j] = o;
}

// ---- fused kernel: gather-weighted accumulate (round-6 inner loop) -> LDS tile -> MFMA fc -> out
__global__ __launch_bounds__(256) void k_gfc(
    const uint16_t* __restrict__ fb,     // (NN, DD) bf16
    const int* __restrict__ paths,       // (PP, NN, LL) int32
    const float* __restrict__ w,         // (LL, DD) f32
    const uint16_t* __restrict__ wb,     // (DD, DD) bf16, row-major (o, d)
    float* __restrict__ out) {           // (NN, DD) f32
  __shared__ int sidx[PP * GN * LL];     // 9216 B
  __shared__ uint16_t sA[GN * WPAD];     // 17408 B
  __shared__ uint16_t sW[DD * WPAD];     // 34816 B   (total 60 KiB)
  const int t = threadIdx.x;
  const int nb = blockIdx.x * GN;

  // stage indices (coalesced)
  #pragma unroll
  for (int s = 0; s < 9; ++s) {          // 2304 / 256
    const int i = s * 256 + t;
    const int p = i / (GN * LL);
    const int rem = i - p * (GN * LL);
    const long g = (long)nb * LL + rem;
    int val = 0;
    if (g < (long)NN * LL) val = paths[(size_t)p * NN * LL + g];
    sidx[i] = val;
  }
  // stage W tile 128x128 bf16 (coalesced uint4)
  #pragma unroll
  for (int it = 0; it < 8; ++it) {
    const int chunk = it * 256 + t;      // 2048 chunks of 8 bf16
    const int row = chunk >> 4, c8 = chunk & 15;
    uint4 v = *(const uint4*)(wb + (size_t)row * DD + c8 * 8);
    *(uint4*)(sW + row * WPAD + c8 * 8) = v;
  }

  const int lane = t & 31;
  const int grp  = t >> 5;               // 0..7
  const int d0   = lane * 4;

  const float sc = 1.f / 6.f;
  f4 wl[LL];
  #pragma unroll
  for (int l = 0; l < LL; ++l) {
    f4 v = *(const f4*)(w + l * DD + d0);
    wl[l].x = v.x * sc; wl[l].y = v.y * sc; wl[l].z = v.z * sc; wl[l].w = v.w * sc;
  }

  __syncthreads();

  // gather: 8 nodes per 32-lane group, 36 row-gathers in flight per node
  #pragma unroll 1
  for (int s = 0; s < 8; ++s) {
    const int ni = grp * 8 + s;
    uint2 v[PP * LL];
    #pragma unroll
    for (int p = 0; p < PP; ++p)
      #pragma unroll
      for (int l = 0; l < LL; ++l) {
        const int idx = sidx[(p * GN + ni) * LL + l];
        v[p * LL + l] = *(const uint2*)(fb + (size_t)idx * DD + d0);  // 4 bf16
      }
    f4 a = {0.f, 0.f, 0.f, 0.f};
    #pragma unroll
    for (int p = 0; p < PP; ++p)
      #pragma unroll
      for (int l = 0; l < LL; ++l) {
        const uint2 u = v[p * LL + l];
        a.x = fmaf(wl[l].x, bf_lo(u.x), a.x);
        a.y = fmaf(wl[l].y, bf_hi(u.x), a.y);
        a.z = fmaf(wl[l].z, bf_lo(u.y), a.z);
        a.w = fmaf(wl[l].w, bf_hi(u.y), a.w);
      }
    ushort4 o;
    o.x = f2bf(a.x); o.y = f2bf(a.y); o.z = f2bf(a.z); o.w = f2bf(a.w);
    *(ushort4*)(sA + ni * WPAD + d0) = o;   // always write (tail rows harmless; guarded at out-store)
  }

  __syncthreads();

  // MFMA fc: wave w owns rows w*16..w*16+15 (round-6 validated mapping)
  const int wv = t >> 6;                  // wave 0..3
  const int l  = t & 63;
  const int lr = l & 15;                  // A-row / B-col / D-col
  const int hk = (l >> 4) * 8;            // k sub-offset

  bf16x8 afrag[4];
  #pragma unroll
  for (int k0 = 0; k0 < 4; ++k0)
    afrag[k0] = *(bf16x8*)(sA + (wv * 16 + lr) * WPAD + k0 * 32 + hk);

  #pragma unroll
  for (int o = 0; o < 8; ++o) {
    f4 dacc = {0.f, 0.f, 0.f, 0.f};
    #pragma unroll
    for (int k0 = 0; k0 < 4; ++k0) {
      bf16x8 bfrag = *(bf16x8*)(sW + (o * 16 + lr) * WPAD + k0 * 32 + hk);
      dacc = __builtin_amdgcn_mfma_f32_16x16x32_bf16(afrag[k0], bfrag, dacc, 0, 0, 0);
    }
    const int col = o * 16 + lr;
    #pragma unroll
    for (int r = 0; r < 4; ++r) {
      const int n = nb + wv * 16 + (l >> 4) * 4 + r;
      if (n < NN) out[(size_t)n * DD + col] = fmaxf(dacc[r], 0.f);
    }
  }
}

extern "C" void kernel_launch(void* const* d_in, const int* in_sizes, int n_in,
                              void* d_out, int out_size, void* d_ws, size_t ws_size,
                              hipStream_t stream) {
  const float* feats = (const float*)d_in[0];
  const int*   paths = (const int*)d_in[1];       // int32 (jax x64 disabled)
  const float* pw1   = (const float*)d_in[4];     // (1,6,128)
  const float* fcw   = (const float*)d_in[6];     // (128,128)
  float* out = (float*)d_out;

  uint16_t* fb = (uint16_t*)d_ws;                                  // 12.8 MB
  uint16_t* wb = (uint16_t*)((char*)d_ws + (size_t)NN * DD * 2);   // 32 KB

  const int n4 = NN * DD / 4;      // 1,600,000
  const int w4 = DD * DD / 4;      // 4,096
  k_cvt<<<(n4 + w4 + 255) / 256, 256, 0, stream>>>(feats, fcw, fb, wb, n4, w4);
  k_gfc<<<(NN + GN - 1) / GN, 256, 0, stream>>>(fb, paths, pw1, wb, out);
}